// Round 3
// baseline (1017.262 us; speedup 1.0000x reference)
//
#include <hip/hip_runtime.h>
#include <cstdint>

typedef short bf8 __attribute__((ext_vector_type(8)));   // 8 x bf16 (bit pattern)
typedef float f4  __attribute__((ext_vector_type(4)));
typedef uint32_t u32x4 __attribute__((ext_vector_type(4)));
typedef unsigned short u16;

__device__ __forceinline__ u16 f2bf(float f) {
  union { float f; uint32_t u; } v; v.f = f;
  uint32_t u = v.u + 0x7fffu + ((v.u >> 16) & 1u);   // RNE
  return (u16)(u >> 16);
}

// pack two f32 -> two bf16 (RNE) in one u32 (lo in low half)
__device__ __forceinline__ uint32_t pk2(float lo, float hi) {
  return (uint32_t)f2bf(lo) | ((uint32_t)f2bf(hi) << 16);
}

// load 8 consecutive f32 (16B-aligned) and convert to a bf16x8 MFMA fragment
__device__ __forceinline__ bf8 ld_cvt8(const float* p) {
  f4 a = *(const f4*)p;
  f4 b = *(const f4*)(p + 4);
  u32x4 r;
  r[0] = pk2(a[0], a[1]);
  r[1] = pk2(a[2], a[3]);
  r[2] = pk2(b[0], b[1]);
  r[3] = pk2(b[2], b[3]);
  return __builtin_bit_cast(bf8, r);
}

template<bool WB>
__device__ __forceinline__ bf8 ldW(const void* p, size_t off) {
  if constexpr (WB) return *(const bf8*)((const u16*)p + off);
  else              return ld_cvt8((const float*)p + off);
}

#define MFMA(a, b, c) __builtin_amdgcn_mfma_f32_16x16x32_bf16((a), (b), (c), 0, 0, 0)

// Problem constants: 1024 groups of (seq=128, C=256), 8 heads of e=32.
constexpr int SEQ = 128;
constexpr int CH  = 256;
constexpr int NH  = 8;

// ---- prepass: convert the 5 weight matrices (f32) to bf16 in workspace ----
// layout (elements): Wq @0 (65536) | Wkv @65536 (131072) | Wout @196608 |
//                    Wsc @262144 | Wsh @327680 ; total 393216 elems.
__global__ void cvt_weights(const float* __restrict__ wq, const float* __restrict__ wkv,
                            const float* __restrict__ wout, const float* __restrict__ wsc,
                            const float* __restrict__ wsh, u16* __restrict__ dst) {
  int i = (blockIdx.x * 256 + threadIdx.x) * 8;   // 0 .. 393208
  const float* s; int off;
  if      (i <  65536) { s = wq;   off = i; }
  else if (i < 196608) { s = wkv;  off = i -  65536; }
  else if (i < 262144) { s = wout; off = i - 196608; }
  else if (i < 327680) { s = wsc;  off = i - 262144; }
  else                 { s = wsh;  off = i - 327680; }
  *(bf8*)(dst + i) = ld_cvt8(s + off);
}

template<bool WB>
__global__ __launch_bounds__(256, 1)
void fused_axattn(const float* __restrict__ x,   const float* __restrict__ ctx,
                  const void* __restrict__ Wq,  const void* __restrict__ Wkv,
                  const void* __restrict__ Wout,const void* __restrict__ Wsc,
                  const void* __restrict__ Wsh, float* __restrict__ out)
{
  __shared__ u16 sQ[SEQ][40];    // Qm, row-major, head-local 32 cols
  __shared__ u16 sK[SEQ][40];    // Km
  __shared__ u16 sVT[32][136];   // Vm transposed: [d][j]
  __shared__ u16 sP[SEQ][136];   // softmax probs (unnormalized), row-major
  __shared__ u16 sO[SEQ][264];   // attention output, all heads (cols 0..255)

  const int tid  = threadIdx.x;
  const int wave = tid >> 6;
  const int lane = tid & 63;
  const int l15  = lane & 15;
  const int quad = lane >> 4;
  const int g    = blockIdx.x;
  const size_t gbase = (size_t)g * (SEQ * CH);
  const int ib = wave * 32;                  // this wave's 32 rows

  const float SCALE = 0.17677669529663687f;  // 1/sqrt(32)

  auto wrow = [&](const void* base, size_t row) -> const void* {
    if constexpr (WB) return (const void*)((const u16*)base + row * CH);
    else              return (const void*)((const float*)base + row * CH);
  };

  float rinv[2][4];                          // per-row 1/softmax-sum

  for (int h = 0; h < NH; ++h) {
    // ===== Phase A: q,k,v,scale,shift as one N=160 MFMA GEMM ======
    // tiles: 0,1=q  2,3=k  4,5=v  6,7=scale  8,9=shift
    f4 acc[2][10];
    #pragma unroll
    for (int mt = 0; mt < 2; ++mt)
      #pragma unroll
      for (int t = 0; t < 10; ++t) acc[mt][t] = 0.0f;

    const int hn0 = h * 32 + l15;
    const void* bp[10];
    bp[0] = wrow(Wq,  hn0);        bp[1] = wrow(Wq,  hn0 + 16);
    bp[2] = wrow(Wkv, hn0);        bp[3] = wrow(Wkv, hn0 + 16);
    bp[4] = wrow(Wkv, hn0 + 256);  bp[5] = wrow(Wkv, hn0 + 272);
    bp[6] = wrow(Wsc, hn0);        bp[7] = wrow(Wsc, hn0 + 16);
    bp[8] = wrow(Wsh, hn0);        bp[9] = wrow(Wsh, hn0 + 16);

    const float* axp = x   + gbase + (size_t)(ib + l15) * CH + quad * 8;
    const float* acp = ctx + gbase + (size_t)(ib + l15) * CH + quad * 8;

    #pragma unroll
    for (int kc = 0; kc < 8; ++kc) {
      const int cc = kc * 32;
      bf8 ax0 = ld_cvt8(axp + cc);
      bf8 ax1 = ld_cvt8(axp + 16 * CH + cc);
      bf8 ac0 = ld_cvt8(acp + cc);
      bf8 ac1 = ld_cvt8(acp + 16 * CH + cc);
      #pragma unroll
      for (int t = 0; t < 10; ++t) {
        bf8 b = ldW<WB>(bp[t], cc + quad * 8);
        bf8 a0 = (t < 6) ? ax0 : ac0;
        bf8 a1 = (t < 6) ? ax1 : ac1;
        acc[0][t] = MFMA(a0, b, acc[0][t]);
        acc[1][t] = MFMA(a1, b, acc[1][t]);
      }
    }

    // FiLM modulation fully in-lane (q/sc/sh tiles share lane layout), write LDS
    #pragma unroll
    for (int mt = 0; mt < 2; ++mt) {
      #pragma unroll
      for (int r = 0; r < 4; ++r) {
        const int i = ib + 16 * mt + 4 * quad + r;
        const float sc0 = acc[mt][6][r], sc1 = acc[mt][7][r];
        const float sh0 = acc[mt][8][r], sh1 = acc[mt][9][r];
        sQ[i][l15]      = f2bf(sc0 * acc[mt][0][r] + sh0);
        sQ[i][16 + l15] = f2bf(sc1 * acc[mt][1][r] + sh1);
        sK[i][l15]      = f2bf(sc0 * acc[mt][2][r] + sh0);
        sK[i][16 + l15] = f2bf(sc1 * acc[mt][3][r] + sh1);
        sVT[l15][i]      = f2bf(sc0 * acc[mt][4][r] + sh0);
        sVT[16 + l15][i] = f2bf(sc1 * acc[mt][5][r] + sh1);
      }
    }
    __syncthreads();

    // ===== S = Qm @ Km^T, softmax in registers =====
    f4 sacc[2][8];
    #pragma unroll
    for (int mt = 0; mt < 2; ++mt) {
      const int i0 = ib + 16 * mt;
      bf8 a = *(const bf8*)(&sQ[i0 + l15][quad * 8]);
      #pragma unroll
      for (int ct = 0; ct < 8; ++ct) {
        bf8 b = *(const bf8*)(&sK[ct * 16 + l15][quad * 8]);
        f4 z = 0.0f;
        sacc[mt][ct] = MFMA(a, b, z);
      }
    }

    #pragma unroll
    for (int mt = 0; mt < 2; ++mt) {
      const int i0 = ib + 16 * mt;
      float mx[4] = {-3.4e38f, -3.4e38f, -3.4e38f, -3.4e38f};
      #pragma unroll
      for (int ct = 0; ct < 8; ++ct)
        #pragma unroll
        for (int r = 0; r < 4; ++r) mx[r] = fmaxf(mx[r], sacc[mt][ct][r]);
      #pragma unroll
      for (int m = 1; m <= 8; m <<= 1)
        #pragma unroll
        for (int r = 0; r < 4; ++r) mx[r] = fmaxf(mx[r], __shfl_xor(mx[r], m));

      float sm[4] = {0.f, 0.f, 0.f, 0.f};
      #pragma unroll
      for (int ct = 0; ct < 8; ++ct)
        #pragma unroll
        for (int r = 0; r < 4; ++r) {
          float p = __expf((sacc[mt][ct][r] - mx[r]) * SCALE);
          sm[r] += p;
          sP[i0 + 4 * quad + r][ct * 16 + l15] = f2bf(p);
        }
      #pragma unroll
      for (int m = 1; m <= 8; m <<= 1)
        #pragma unroll
        for (int r = 0; r < 4; ++r) sm[r] += __shfl_xor(sm[r], m);
      #pragma unroll
      for (int r = 0; r < 4; ++r) rinv[mt][r] = 1.0f / sm[r];
    }
    __syncthreads();

    // ===== O_h = P @ Vm (normalize at write) =====
    #pragma unroll
    for (int mt = 0; mt < 2; ++mt) {
      const int i0 = ib + 16 * mt;
      #pragma unroll
      for (int dt = 0; dt < 2; ++dt) {
        f4 o = 0.0f;
        #pragma unroll
        for (int kt = 0; kt < 4; ++kt) {
          bf8 a = *(const bf8*)(&sP[i0 + l15][kt * 32 + quad * 8]);
          bf8 b = *(const bf8*)(&sVT[dt * 16 + l15][kt * 32 + quad * 8]);
          o = MFMA(a, b, o);
        }
        #pragma unroll
        for (int r = 0; r < 4; ++r)
          sO[i0 + 4 * quad + r][h * 32 + dt * 16 + l15] = f2bf(o[r] * rinv[mt][r]);
      }
    }
    __syncthreads();
  }

  // ===== Out projection: (128x256) @ Wout^T, f32 store =====
  f4 pacc[2][16];
  #pragma unroll
  for (int mt = 0; mt < 2; ++mt)
    #pragma unroll
    for (int nt = 0; nt < 16; ++nt) pacc[mt][nt] = 0.0f;

  #pragma unroll
  for (int kc = 0; kc < 8; ++kc) {
    const int cc = kc * 32;
    bf8 a0 = *(const bf8*)(&sO[ib + l15][cc + quad * 8]);
    bf8 a1 = *(const bf8*)(&sO[ib + 16 + l15][cc + quad * 8]);
    #pragma unroll
    for (int nt = 0; nt < 16; ++nt) {
      bf8 b = ldW<WB>(wrow(Wout, nt * 16 + l15), cc + quad * 8);
      pacc[0][nt] = MFMA(a0, b, pacc[0][nt]);
      pacc[1][nt] = MFMA(a1, b, pacc[1][nt]);
    }
  }

  #pragma unroll
  for (int mt = 0; mt < 2; ++mt)
    #pragma unroll
    for (int nt = 0; nt < 16; ++nt)
      #pragma unroll
      for (int r = 0; r < 4; ++r)
        out[gbase + (size_t)(ib + 16 * mt + 4 * quad + r) * CH + nt * 16 + l15] =
            pacc[mt][nt][r];
}

extern "C" void kernel_launch(void* const* d_in, const int* in_sizes, int n_in,
                              void* d_out, int out_size, void* d_ws, size_t ws_size,
                              hipStream_t stream) {
  const float* x    = (const float*)d_in[0];
  const float* ctx  = (const float*)d_in[1];
  const float* Wq   = (const float*)d_in[2];
  const float* Wkv  = (const float*)d_in[3];
  const float* Wout = (const float*)d_in[4];
  const float* Wsc  = (const float*)d_in[5];
  const float* Wsh  = (const float*)d_in[6];
  float* o = (float*)d_out;

  if (ws_size >= 393216u * sizeof(u16)) {
    u16* w = (u16*)d_ws;
    cvt_weights<<<dim3(192), dim3(256), 0, stream>>>(Wq, Wkv, Wout, Wsc, Wsh, w);
    fused_axattn<true><<<dim3(1024), dim3(256), 0, stream>>>(
        x, ctx, w, w + 65536, w + 196608, w + 262144, w + 327680, o);
  } else {
    fused_axattn<false><<<dim3(1024), dim3(256), 0, stream>>>(
        x, ctx, Wq, Wkv, Wout, Wsc, Wsh, o);
  }
}